// Round 11
// baseline (80.697 us; speedup 1.0000x reference)
//
#include <hip/hip_runtime.h>
#include <hip/hip_bf16.h>

#define B_ 16
#define C_ 64
#define HW_ 4096              // H*W
#define K_ 1024
#define NELEM 4194304         // B*C*H*W
#define NBLK 1024             // 64 pixels per block

typedef __attribute__((ext_vector_type(8))) short bf16x8;
typedef __attribute__((ext_vector_type(4))) float f32x4;

static __device__ __forceinline__ short f2bf(float f) {
    __hip_bfloat16 h = __float2bfloat16(f);           // RNE, native cvt
    return (short)__builtin_bit_cast(unsigned short, h);
}

// ---- kernel 1: emb -> fragment-contiguous bf16(-2*emb) + e2' + cnt=0 -----
// Fragment layout (shorts): q*16384 + ch*2048 + (ct*2+half)*512 + lane*8,
// lane = kgrp*16 + prow; code = q*256+ch*32+ct*16+prow; dims = half*32+kgrp*8.
// A wave's fragments are coalesced 16B/lane loads at stride 512 shorts.
__global__ __launch_bounds__(256) void vq_prep(const float* __restrict__ emb,
                                               float* __restrict__ e2,
                                               short* __restrict__ emb_q,
                                               int* __restrict__ cnt) {
    const int id = blockIdx.x * 256 + threadIdx.x;    // 0..8191
    if (id == 0) *cnt = 0;
    {   // -2x scale is exact in bf16 (sign + exponent shift)
        const int code = id >> 3;
        const int c16  = id & 7;                      // 16B group in row
        const float4* src = (const float4*)(emb + (size_t)id * 8);
        float4 a = src[0], b = src[1];
        bf16x8 v;
        v[0]=f2bf(-2.f*a.x); v[1]=f2bf(-2.f*a.y); v[2]=f2bf(-2.f*a.z); v[3]=f2bf(-2.f*a.w);
        v[4]=f2bf(-2.f*b.x); v[5]=f2bf(-2.f*b.y); v[6]=f2bf(-2.f*b.z); v[7]=f2bf(-2.f*b.w);
        const int q    = code >> 8;
        const int ch   = (code >> 5) & 7;
        const int ct   = (code >> 4) & 1;
        const int prow = code & 15;
        const int half = c16 >> 2;
        const int kgrp = c16 & 3;
        const int dst = q * 16384 + ch * 2048 + (ct * 2 + half) * 512
                      + (kgrp * 16 + prow) * 8;
        *(bf16x8*)(emb_q + dst) = v;
    }
    if (id < K_) {
        const float4* row = (const float4*)(emb + (size_t)id * C_);
        float s0 = 0.f, s1 = 0.f, s2 = 0.f, s3 = 0.f;
        #pragma unroll
        for (int i = 0; i < C_ / 4; ++i) {
            float4 v = row[i];
            s0 = fmaf(v.x, v.x, s0);
            s1 = fmaf(v.y, v.y, s1);
            s2 = fmaf(v.z, v.z, s2);
            s3 = fmaf(v.w, v.w, s3);
        }
        e2[id] = 1.0f + ((s0 + s1) + (s2 + s3));   // keeps dist' > 0
    }
}

// ---- kernel 2: fused MFMA argmin + gather + q_st + loss (+last-block) ----
// Block = 256 thr = 4 waves, owns 64 consecutive pixels (same b).
// Wave qd scans K-quadrant [qd*256,...+256); A-fragments GLOBAL->REG from
// fragment-contiguous emb_q; no emb LDS, no main-loop barriers.
// launch_bounds(256,4): FORCES combined VGPR+AGPR <= 128 so 4 waves/SIMD
// are actually resident (R10's (256,2) let regalloc hoist to ~256 combined
// -> 2 waves/SIMD -> latency-bound at 55us). Natural footprint ~90, fits.
//   D[row=code][col=pixel] = 1 + |e|^2 - 2 z.e  (positive)
// Select: sortable int = (bits(dist) & ~1023) | k ; argmin = v_min_i32.
__global__ __launch_bounds__(256, 4) void vq_main(const float* __restrict__ z,
                                                  const float* __restrict__ emb,
                                                  const short* __restrict__ emb_q,
                                                  const float* __restrict__ e2,
                                                  float* __restrict__ out,
                                                  float* __restrict__ psum,
                                                  int* __restrict__ cnt) {
    __shared__ short zlds[64 * 64];    // 8 KB, [px][ch], col ^= (px&7)<<4
    __shared__ int   smin[4][64];
    __shared__ int   cidx[64];
    __shared__ float red[4];
    __shared__ int   isLast;

    const int tid  = threadIdx.x;
    const int lane = tid & 63;
    const int qd   = __builtin_amdgcn_readfirstlane(tid >> 6);  // wave = quadrant
    const int prow = lane & 15;        // code-in-tile row
    const int kgrp = lane >> 4;        // k-group 0..3

    const int blk = blockIdx.x;        // 0..1023
    const int b   = blk >> 6;          // 64 blocks per image
    const int hw0 = (blk & 63) * 64;
    const float* zp = z + (size_t)b * C_ * HW_ + hw0;   // + c*HW_ + p

    // ---- stage z -> swizzled LDS bf16 (each thread: 16 ch of one pixel) --
    {
        const int p  = tid & 63;
        const int c0 = tid >> 6;               // 0..3
        #pragma unroll
        for (int h = 0; h < 2; ++h) {
            const int cb = c0 * 16 + h * 8;    // channel base
            bf16x8 pack;
            #pragma unroll
            for (int i = 0; i < 8; ++i) pack[i] = f2bf(zp[(size_t)(cb + i) * HW_ + p]);
            const int wb = (p * 128 + ((cb * 2) ^ ((p & 7) << 4))) >> 1;
            *(bf16x8*)(zlds + wb) = pack;
        }
    }
    __syncthreads();

    // ---- z fragments (B operand): 4 pixel tiles x 2 K-halves ----
    bf16x8 zf[4][2];
    #pragma unroll
    for (int pt = 0; pt < 4; ++pt) {
        const int pp = pt * 16 + prow;
        #pragma unroll
        for (int ks = 0; ks < 2; ++ks) {
            const int rb = (pp * 128 + ((ks * 64 + kgrp * 16) ^ ((pp & 7) << 4))) >> 1;
            zf[pt][ks] = *(const bf16x8*)(zlds + rb);
        }
    }

    // ---- per-wave argmin over its 256-code quadrant, global->reg A ----
    const short* eq  = emb_q + qd * 16384 + lane * 8;   // + ch*2048 + f*512
    const float* e2q = e2 + qd * 256 + kgrp * 4;        // + ch*32 + ct*16
    int best[4] = {0x7FFFFFFF, 0x7FFFFFFF, 0x7FFFFFFF, 0x7FFFFFFF};

    #pragma unroll
    for (int ch = 0; ch < 8; ++ch) {
        #pragma unroll
        for (int ct = 0; ct < 2; ++ct) {
            const bf16x8 a0 = *(const bf16x8*)(eq + ch * 2048 + (ct * 2 + 0) * 512);
            const bf16x8 a1 = *(const bf16x8*)(eq + ch * 2048 + (ct * 2 + 1) * 512);
            const f32x4  ev = *(const f32x4*)(e2q + ch * 32 + ct * 16);
            const int korg = qd * 256 + ch * 32 + ct * 16 + kgrp * 4;
            #pragma unroll
            for (int pt = 0; pt < 4; ++pt) {
                f32x4 acc = ev;
                acc = __builtin_amdgcn_mfma_f32_16x16x32_bf16(a0, zf[pt][0], acc, 0, 0, 0);
                acc = __builtin_amdgcn_mfma_f32_16x16x32_bf16(a1, zf[pt][1], acc, 0, 0, 0);
                #pragma unroll
                for (int r = 0; r < 4; ++r) {
                    const int s = (__builtin_bit_cast(int, acc[r]) & ~1023) | (korg + r);
                    best[pt] = min(best[pt], s);
                }
            }
        }
    }

    // cross-lane combine over k-groups (bits 4,5 of lane)
    #pragma unroll
    for (int pt = 0; pt < 4; ++pt) {
        #pragma unroll
        for (int m = 16; m <= 32; m <<= 1)
            best[pt] = min(best[pt], __shfl_xor(best[pt], m));
        if (kgrp == 0) smin[qd][pt * 16 + prow] = best[pt];
    }
    __syncthreads();

    // cross-wave combine (4 quadrant-waves)
    if (tid < 64) {
        int bb = min(min(smin[0][tid], smin[1][tid]),
                     min(smin[2][tid], smin[3][tid]));
        cidx[tid] = bb & 1023;
    }
    __syncthreads();

    // ---- output phase: q_st = z + (q - z), partial loss ----
    float* op = out + (size_t)b * C_ * HW_ + hw0;
    const int p  = tid & 63;
    const int c0 = tid >> 6;                  // 0..3
    const float* qrow = emb + (size_t)cidx[p] * C_;
    float sq = 0.f;
    #pragma unroll
    for (int i = 0; i < 16; ++i) {
        const int c = c0 * 16 + i;
        const float zv   = zp[(size_t)c * HW_ + p];
        const float q    = qrow[c];
        const float diff = q - zv;            // matches reference op order
        op[(size_t)c * HW_ + p] = zv + diff;  // q_st = z + (q - z)
        sq = fmaf(diff, diff, sq);
    }
    #pragma unroll
    for (int off = 32; off; off >>= 1) sq += __shfl_xor(sq, off);
    if (lane == 0) red[tid >> 6] = sq;
    __syncthreads();
    if (tid == 0) {
        psum[blk] = (red[0] + red[1]) + (red[2] + red[3]);
        __threadfence();                      // psum visible device-wide
        isLast = (atomicAdd(cnt, 1) == NBLK - 1);
    }
    __syncthreads();

    // ---- last block reduces psum -> loss (fixed order => deterministic) --
    if (isLast) {
        __threadfence();
        float s = (psum[tid] + psum[tid + 256]) + (psum[tid + 512] + psum[tid + 768]);
        #pragma unroll
        for (int off = 32; off; off >>= 1) s += __shfl_xor(s, off);
        if (lane == 0) red[tid >> 6] = s;
        __syncthreads();
        if (tid == 0)
            out[NELEM] = 1.25f * ((red[0] + red[1]) + (red[2] + red[3])) / (float)NELEM;
    }
}

extern "C" void kernel_launch(void* const* d_in, const int* in_sizes, int n_in,
                              void* d_out, int out_size, void* d_ws, size_t ws_size,
                              hipStream_t stream) {
    const float* z   = (const float*)d_in[0];   // [16,64,64,64]
    const float* emb = (const float*)d_in[1];   // [1024,64]
    float* out = (float*)d_out;                 // [4194304 q_st] ++ [1 loss]

    float* psum  = (float*)d_ws;                // 1024 floats
    float* e2    = psum + NBLK;                 // 1024 floats (e2' = 1+|e|^2)
    int*   cnt   = (int*)(e2 + K_);             // 1 int (+pad to 16B)
    short* emb_q = (short*)(cnt + 4);           // 65536 bf16, fragment layout

    vq_prep<<<(K_ * C_) / (256 * 8), 256, 0, stream>>>(emb, e2, emb_q, cnt);
    vq_main<<<NBLK, 256, 0, stream>>>(z, emb, emb_q, e2, out, psum, cnt);
}

// Round 12
// 75.529 us; speedup vs baseline: 1.0684x; 1.0684x over previous
//
#include <hip/hip_runtime.h>
#include <hip/hip_bf16.h>

#define B_ 16
#define C_ 64
#define HW_ 4096              // H*W
#define K_ 1024
#define NELEM 4194304         // B*C*H*W
#define NBLK 1024             // 64 pixels per block

typedef __attribute__((ext_vector_type(8))) short bf16x8;
typedef __attribute__((ext_vector_type(4))) float f32x4;
typedef unsigned int u32;

static __device__ __forceinline__ short f2bf(float f) {
    __hip_bfloat16 h = __float2bfloat16(f);           // RNE, native cvt
    return (short)__builtin_bit_cast(unsigned short, h);
}

// global -> LDS async copy, 16B per lane; dest wave-uniform base (HW adds lane*16).
static __device__ __forceinline__ void gl_lds16(const short* g, short* l) {
    __builtin_amdgcn_global_load_lds(
        (const __attribute__((address_space(1))) u32*)g,
        (__attribute__((address_space(3))) u32*)l, 16, 0, 0);
}

// ---- kernel 1: emb -> fragment-contiguous bf16(-2*emb) + e2' + cnt=0 -----
// Layout (shorts): q*16384 + ch*2048 + (ct*2+half)*512 + (kgrp*16+prow)*8.
// code = q*256+ch*32+ct*16+prow; dims = half*32+kgrp*8. Each 512-short span
// is one 1KB gl_lds (64 lanes x 16B), and ds_read at lane*16B is linear ->
// conflict-free without any swizzle.
__global__ __launch_bounds__(256) void vq_prep(const float* __restrict__ emb,
                                               float* __restrict__ e2,
                                               short* __restrict__ emb_q,
                                               int* __restrict__ cnt) {
    const int id = blockIdx.x * 256 + threadIdx.x;    // 0..8191
    if (id == 0) *cnt = 0;
    {   // -2x scale is exact in bf16 (sign + exponent shift)
        const int code = id >> 3;
        const int c16  = id & 7;                      // 16B group in row
        const float4* src = (const float4*)(emb + (size_t)id * 8);
        float4 a = src[0], b = src[1];
        bf16x8 v;
        v[0]=f2bf(-2.f*a.x); v[1]=f2bf(-2.f*a.y); v[2]=f2bf(-2.f*a.z); v[3]=f2bf(-2.f*a.w);
        v[4]=f2bf(-2.f*b.x); v[5]=f2bf(-2.f*b.y); v[6]=f2bf(-2.f*b.z); v[7]=f2bf(-2.f*b.w);
        const int q    = code >> 8;
        const int ch   = (code >> 5) & 7;
        const int ct   = (code >> 4) & 1;
        const int prow = code & 15;
        const int half = c16 >> 2;
        const int kgrp = c16 & 3;
        const int dst = q * 16384 + ch * 2048 + (ct * 2 + half) * 512
                      + (kgrp * 16 + prow) * 8;
        *(bf16x8*)(emb_q + dst) = v;
    }
    if (id < K_) {
        const float4* row = (const float4*)(emb + (size_t)id * C_);
        float s0 = 0.f, s1 = 0.f, s2 = 0.f, s3 = 0.f;
        #pragma unroll
        for (int i = 0; i < C_ / 4; ++i) {
            float4 v = row[i];
            s0 = fmaf(v.x, v.x, s0);
            s1 = fmaf(v.y, v.y, s1);
            s2 = fmaf(v.z, v.z, s2);
            s3 = fmaf(v.w, v.w, s3);
        }
        e2[id] = 1.0f + ((s0 + s1) + (s2 + s3));   // keeps dist' > 0
    }
}

// ---- kernel 2: fused MFMA argmin + gather + q_st + loss (+last-block) ----
// Block = 256 thr = 4 waves, 64 pixels. Wave qd owns K-quadrant qd.
// WAVE-PRIVATE double-buffered LDS emb staging via global_load_lds:
// no wave reads another wave's staged data => ZERO barriers in the main
// loop; ordering is the wave's own counted s_waitcnt vmcnt(4) (stage(t+1)'s
// 4 loads stay in flight across the wait — T4, never vmcnt(0) mid-loop).
//   D[row=code][col=pixel] = 1 + |e|^2 - 2 z.e  (positive)
// Select: sortable int = (bits(dist) & ~1023) | k ; argmin = v_min_i32.
__global__ __launch_bounds__(256, 3) void vq_main(const float* __restrict__ z,
                                                  const float* __restrict__ emb,
                                                  const short* __restrict__ emb_q,
                                                  const float* __restrict__ e2,
                                                  float* __restrict__ out,
                                                  float* __restrict__ psum,
                                                  int* __restrict__ cnt) {
    __shared__ short zlds[64 * 64];       // 8 KB, [px][ch], col ^= (px&7)<<4
    __shared__ short embuf[8][2048];      // 4 waves x 2 bufs x 4 KB = 32 KB
    __shared__ float e2lds[K_];           // 4 KB
    __shared__ int   smin[4][64];
    __shared__ int   cidx[64];
    __shared__ float red[4];
    __shared__ int   isLast;

    const int tid  = threadIdx.x;
    const int lane = tid & 63;
    const int qd   = __builtin_amdgcn_readfirstlane(tid >> 6);  // wave = quadrant
    const int prow = lane & 15;        // code-in-tile row
    const int kgrp = lane >> 4;        // k-group 0..3

    const int blk = blockIdx.x;        // 0..1023
    const int b   = blk >> 6;          // 64 blocks per image
    const int hw0 = (blk & 63) * 64;
    const float* zp = z + (size_t)b * C_ * HW_ + hw0;   // + c*HW_ + p

    // ---- stage z -> swizzled LDS bf16 (each thread: 16 ch of one pixel) --
    {
        const int p  = tid & 63;
        const int c0 = tid >> 6;               // 0..3
        #pragma unroll
        for (int h = 0; h < 2; ++h) {
            const int cb = c0 * 16 + h * 8;    // channel base
            bf16x8 pack;
            #pragma unroll
            for (int i = 0; i < 8; ++i) pack[i] = f2bf(zp[(size_t)(cb + i) * HW_ + p]);
            const int wb = (p * 128 + ((cb * 2) ^ ((p & 7) << 4))) >> 1;
            *(bf16x8*)(zlds + wb) = pack;
        }
    }
    // ---- stage e2' ----
    #pragma unroll
    for (int i = 0; i < 4; ++i) e2lds[i * 256 + tid] = e2[i * 256 + tid];

    // ---- prologue: stage chunk 0 into private buf 0 ----
    const short* eqg = emb_q + qd * 16384 + lane * 8;   // + ch*2048 + f*512
    short* eb0 = &embuf[qd * 2 + 0][0];
    short* eb1 = &embuf[qd * 2 + 1][0];
    #pragma unroll
    for (int f = 0; f < 4; ++f) gl_lds16(eqg + f * 512, eb0 + f * 512);

    __syncthreads();   // zlds/e2lds visible; drains prologue stage (once)

    // ---- z fragments (B operand): 4 pixel tiles x 2 K-halves ----
    bf16x8 zf[4][2];
    #pragma unroll
    for (int pt = 0; pt < 4; ++pt) {
        const int pp = pt * 16 + prow;
        #pragma unroll
        for (int ks = 0; ks < 2; ++ks) {
            const int rb = (pp * 128 + ((ks * 64 + kgrp * 16) ^ ((pp & 7) << 4))) >> 1;
            zf[pt][ks] = *(const bf16x8*)(zlds + rb);
        }
    }

    const float* e2w = e2lds + qd * 256 + kgrp * 4;
    int best[4] = {0x7FFFFFFF, 0x7FFFFFFF, 0x7FFFFFFF, 0x7FFFFFFF};

    #pragma unroll
    for (int ch = 0; ch < 8; ++ch) {           // full unroll: static bufs
        if (ch < 7) {                          // issue next stage FIRST
            short* dst = (ch & 1) ? eb0 : eb1; // buf (ch+1)&1
            const short* src = eqg + (ch + 1) * 2048;
            #pragma unroll
            for (int f = 0; f < 4; ++f) gl_lds16(src + f * 512, dst + f * 512);
        }
        // own-wave counted wait: stage(ch) landed, stage(ch+1) in flight
        if (ch >= 1 && ch < 7) {
            asm volatile("s_waitcnt vmcnt(4)" ::: "memory");
            __builtin_amdgcn_sched_barrier(0);
        } else if (ch == 7) {
            asm volatile("s_waitcnt vmcnt(0)" ::: "memory");
            __builtin_amdgcn_sched_barrier(0);
        }
        const short* ebc = (ch & 1) ? eb1 : eb0;
        #pragma unroll
        for (int ct = 0; ct < 2; ++ct) {
            const bf16x8 a0 = *(const bf16x8*)(ebc + (ct * 2 + 0) * 512 + lane * 8);
            const bf16x8 a1 = *(const bf16x8*)(ebc + (ct * 2 + 1) * 512 + lane * 8);
            const f32x4  ev = *(const f32x4*)(e2w + ch * 32 + ct * 16);
            const int korg = qd * 256 + ch * 32 + ct * 16 + kgrp * 4;
            #pragma unroll
            for (int pt = 0; pt < 4; ++pt) {
                f32x4 acc = ev;
                acc = __builtin_amdgcn_mfma_f32_16x16x32_bf16(a0, zf[pt][0], acc, 0, 0, 0);
                acc = __builtin_amdgcn_mfma_f32_16x16x32_bf16(a1, zf[pt][1], acc, 0, 0, 0);
                #pragma unroll
                for (int r = 0; r < 4; ++r) {
                    const int s = (__builtin_bit_cast(int, acc[r]) & ~1023) | (korg + r);
                    best[pt] = min(best[pt], s);
                }
            }
        }
    }

    // cross-lane combine over k-groups (bits 4,5 of lane)
    #pragma unroll
    for (int pt = 0; pt < 4; ++pt) {
        #pragma unroll
        for (int m = 16; m <= 32; m <<= 1)
            best[pt] = min(best[pt], __shfl_xor(best[pt], m));
        if (kgrp == 0) smin[qd][pt * 16 + prow] = best[pt];
    }
    __syncthreads();

    // cross-wave combine (4 quadrant-waves)
    if (tid < 64) {
        int bb = min(min(smin[0][tid], smin[1][tid]),
                     min(smin[2][tid], smin[3][tid]));
        cidx[tid] = bb & 1023;
    }
    __syncthreads();

    // ---- output phase: q_st = z + (q - z), partial loss ----
    float* op = out + (size_t)b * C_ * HW_ + hw0;
    const int p  = tid & 63;
    const int c0 = tid >> 6;                  // 0..3
    const float* qrow = emb + (size_t)cidx[p] * C_;
    float sq = 0.f;
    #pragma unroll
    for (int i = 0; i < 16; ++i) {
        const int c = c0 * 16 + i;
        const float zv   = zp[(size_t)c * HW_ + p];
        const float q    = qrow[c];
        const float diff = q - zv;            // matches reference op order
        op[(size_t)c * HW_ + p] = zv + diff;  // q_st = z + (q - z)
        sq = fmaf(diff, diff, sq);
    }
    #pragma unroll
    for (int off = 32; off; off >>= 1) sq += __shfl_xor(sq, off);
    if (lane == 0) red[tid >> 6] = sq;
    __syncthreads();
    if (tid == 0) {
        psum[blk] = (red[0] + red[1]) + (red[2] + red[3]);
        __threadfence();                      // psum visible device-wide
        isLast = (atomicAdd(cnt, 1) == NBLK - 1);
    }
    __syncthreads();

    // ---- last block reduces psum -> loss (fixed order => deterministic) --
    if (isLast) {
        __threadfence();
        float s = (psum[tid] + psum[tid + 256]) + (psum[tid + 512] + psum[tid + 768]);
        #pragma unroll
        for (int off = 32; off; off >>= 1) s += __shfl_xor(s, off);
        if (lane == 0) red[tid >> 6] = s;
        __syncthreads();
        if (tid == 0)
            out[NELEM] = 1.25f * ((red[0] + red[1]) + (red[2] + red[3])) / (float)NELEM;
    }
}

extern "C" void kernel_launch(void* const* d_in, const int* in_sizes, int n_in,
                              void* d_out, int out_size, void* d_ws, size_t ws_size,
                              hipStream_t stream) {
    const float* z   = (const float*)d_in[0];   // [16,64,64,64]
    const float* emb = (const float*)d_in[1];   // [1024,64]
    float* out = (float*)d_out;                 // [4194304 q_st] ++ [1 loss]

    float* psum  = (float*)d_ws;                // 1024 floats
    float* e2    = psum + NBLK;                 // 1024 floats (e2' = 1+|e|^2)
    int*   cnt   = (int*)(e2 + K_);             // 1 int (+pad to 16B)
    short* emb_q = (short*)(cnt + 4);           // 65536 bf16, fragment layout

    vq_prep<<<(K_ * C_) / (256 * 8), 256, 0, stream>>>(emb, e2, emb_q, cnt);
    vq_main<<<NBLK, 256, 0, stream>>>(z, emb, emb_q, e2, out, psum, cnt);
}

// Round 13
// 54.628 us; speedup vs baseline: 1.4772x; 1.3826x over previous
//
#include <hip/hip_runtime.h>
#include <hip/hip_bf16.h>

#define B_ 16
#define C_ 64
#define HW_ 4096              // H*W
#define K_ 1024
#define NELEM 4194304         // B*C*H*W
#define NBLK 1024             // 64 pixels per block

typedef __attribute__((ext_vector_type(8))) short bf16x8;
typedef __attribute__((ext_vector_type(4))) float f32x4;
typedef unsigned int u32;

static __device__ __forceinline__ short f2bf(float f) {
    __hip_bfloat16 h = __float2bfloat16(f);           // RNE, native cvt
    return (short)__builtin_bit_cast(unsigned short, h);
}

// global -> LDS async copy, 16B per lane; dest wave-uniform base (HW adds lane*16).
static __device__ __forceinline__ void gl_lds16(const short* g, short* l) {
    __builtin_amdgcn_global_load_lds(
        (const __attribute__((address_space(1))) u32*)g,
        (__attribute__((address_space(3))) u32*)l, 16, 0, 0);
}

// ---- kernel 1: emb -> chunked fragment-contiguous bf16(-2*emb) + e2' -----
// 16 chunks x 64 codes (16 per quadrant). Layout (shorts):
//   ch*4096 + q*1024 + half*512 + (kgrp*16+prow)*8
// code = q*256 + ch*16 + prow ; dims = half*32 + kgrp*8 + j.
// Each 512-short span = one 1KB gl_lds (64 lanes x 16B); ds_read at lane*16B
// is linear -> conflict-free, no swizzle needed.
__global__ __launch_bounds__(256) void vq_prep(const float* __restrict__ emb,
                                               float* __restrict__ e2,
                                               short* __restrict__ emb_q,
                                               int* __restrict__ cnt) {
    const int id = blockIdx.x * 256 + threadIdx.x;    // 0..8191
    if (id == 0) *cnt = 0;
    {   // -2x scale is exact in bf16 (sign + exponent shift)
        const int code = id >> 3;
        const int c16  = id & 7;                      // 16B group in row
        const float4* src = (const float4*)(emb + (size_t)id * 8);
        float4 a = src[0], b = src[1];
        bf16x8 v;
        v[0]=f2bf(-2.f*a.x); v[1]=f2bf(-2.f*a.y); v[2]=f2bf(-2.f*a.z); v[3]=f2bf(-2.f*a.w);
        v[4]=f2bf(-2.f*b.x); v[5]=f2bf(-2.f*b.y); v[6]=f2bf(-2.f*b.z); v[7]=f2bf(-2.f*b.w);
        const int q    = code >> 8;
        const int ch   = (code >> 4) & 15;
        const int prow = code & 15;
        const int half = c16 >> 2;
        const int kgrp = c16 & 3;
        const int dst  = ch * 4096 + q * 1024 + half * 512 + (kgrp * 16 + prow) * 8;
        *(bf16x8*)(emb_q + dst) = v;
    }
    if (id < K_) {
        const float4* row = (const float4*)(emb + (size_t)id * C_);
        float s0 = 0.f, s1 = 0.f, s2 = 0.f, s3 = 0.f;
        #pragma unroll
        for (int i = 0; i < C_ / 4; ++i) {
            float4 v = row[i];
            s0 = fmaf(v.x, v.x, s0);
            s1 = fmaf(v.y, v.y, s1);
            s2 = fmaf(v.z, v.z, s2);
            s3 = fmaf(v.w, v.w, s3);
        }
        e2[id] = 1.0f + ((s0 + s1) + (s2 + s3));   // keeps dist' > 0
    }
}

// ---- kernel 2: fused MFMA argmin + gather + q_st + loss (+last-block) ----
// Block = 256 thr = 4 waves, 64 pixels. Wave qd owns K-quadrant qd.
// TRIPLE-buffered 8KB emb chunks, cooperative gl_lds staging.
// Per chunk: [s_waitcnt vmcnt(2) (counted: stage(t+1) stays in flight)]
//            [raw s_barrier — NO drain] [issue stage(t+2) into freed buf]
//            [compute chunk t].  One barrier/chunk, vmcnt never 0 mid-loop.
//   D[row=code][col=pixel] = 1 + |e|^2 - 2 z.e  (positive)
// Select: sortable int = (bits(dist) & ~1023) | k ; argmin = v_min_i32.
// LDS 37.5 KB + VGPR<=128 -> 4 blocks/CU (16 waves/CU), ~2-chunk pipeline.
__global__ __launch_bounds__(256, 4) void vq_main(const float* __restrict__ z,
                                                  const float* __restrict__ emb,
                                                  const short* __restrict__ emb_q,
                                                  const float* __restrict__ e2,
                                                  float* __restrict__ out,
                                                  float* __restrict__ psum,
                                                  int* __restrict__ cnt) {
    __shared__ short zlds[64 * 64];       // 8 KB, [px][ch], col ^= (px&7)<<4
    __shared__ short embuf[3][4096];      // 3 x 8 KB chunk triple-buffer
    __shared__ float e2lds[K_];           // 4 KB (plain layout)
    __shared__ int   smin[4][64];
    __shared__ int   cidx[64];
    __shared__ float red[4];
    __shared__ int   isLast;

    const int tid  = threadIdx.x;
    const int lane = tid & 63;
    const int qd   = __builtin_amdgcn_readfirstlane(tid >> 6);  // wave = quadrant
    const int prow = lane & 15;        // code-in-tile row
    const int kgrp = lane >> 4;        // k-group 0..3

    const int blk = blockIdx.x;        // 0..1023
    const int b   = blk >> 6;          // 64 blocks per image
    const int hw0 = (blk & 63) * 64;
    const float* zp = z + (size_t)b * C_ * HW_ + hw0;   // + c*HW_ + p

    // ---- prologue: stage chunks 0 and 1 (overlaps the z staging below) ---
    const short* eqg = emb_q + qd * 1024 + lane * 8;    // + ch*4096 (+half*512)
    {
        short* d0 = &embuf[0][qd * 1024];
        gl_lds16(eqg,        d0);
        gl_lds16(eqg + 512,  d0 + 512);
        short* d1 = &embuf[1][qd * 1024];
        gl_lds16(eqg + 4096,       d1);
        gl_lds16(eqg + 4096 + 512, d1 + 512);
    }

    // ---- stage z -> swizzled LDS bf16 (each thread: 16 ch of one pixel) --
    {
        const int p  = tid & 63;
        const int c0 = tid >> 6;               // 0..3
        #pragma unroll
        for (int h = 0; h < 2; ++h) {
            const int cb = c0 * 16 + h * 8;    // channel base
            bf16x8 pack;
            #pragma unroll
            for (int i = 0; i < 8; ++i) pack[i] = f2bf(zp[(size_t)(cb + i) * HW_ + p]);
            const int wb = (p * 128 + ((cb * 2) ^ ((p & 7) << 4))) >> 1;
            *(bf16x8*)(zlds + wb) = pack;
        }
    }
    // ---- stage e2' ----
    #pragma unroll
    for (int i = 0; i < 4; ++i) e2lds[i * 256 + tid] = e2[i * 256 + tid];

    __syncthreads();   // zlds/e2lds visible; prologue stages drained (once)

    // ---- z fragments (B operand): 4 pixel tiles x 2 K-halves ----
    bf16x8 zf[4][2];
    #pragma unroll
    for (int pt = 0; pt < 4; ++pt) {
        const int pp = pt * 16 + prow;
        #pragma unroll
        for (int ks = 0; ks < 2; ++ks) {
            const int rb = (pp * 128 + ((ks * 64 + kgrp * 16) ^ ((pp & 7) << 4))) >> 1;
            zf[pt][ks] = *(const bf16x8*)(zlds + rb);
        }
    }

    const int lbase = qd * 1024 + lane * 8;   // this wave's ds_read base
    int best[4] = {0x7FFFFFFF, 0x7FFFFFFF, 0x7FFFFFFF, 0x7FFFFFFF};

    short* bA = &embuf[0][0];   // compute buffer (chunk t)
    short* bB = &embuf[1][0];   // in flight      (chunk t+1)
    short* bC = &embuf[2][0];   // free -> stage  (chunk t+2)

    #pragma unroll 1
    for (int ch = 0; ch < 16; ++ch) {
        // counted wait: own stage(ch) landed; stage(ch+1)'s 2 loads in flight
        asm volatile("s_waitcnt vmcnt(2)" ::: "memory");
        __builtin_amdgcn_sched_barrier(0);
        __builtin_amdgcn_s_barrier();         // all waves' stage(ch) landed
        if (ch < 14) {                        // stage(ch+2) into freed buf
            const short* src = eqg + (ch + 2) * 4096;
            short* d = bC + qd * 1024;
            gl_lds16(src,       d);
            gl_lds16(src + 512, d + 512);
        }
        // ---- compute chunk ch: 1 code-tile (16 codes) x 4 pixel tiles ----
        const bf16x8 a0 = *(const bf16x8*)(bA + lbase);
        const bf16x8 a1 = *(const bf16x8*)(bA + lbase + 512);
        const int korg = qd * 256 + ch * 16 + kgrp * 4;
        const f32x4 ev = *(const f32x4*)(e2lds + korg);
        #pragma unroll
        for (int pt = 0; pt < 4; ++pt) {
            f32x4 acc = ev;
            acc = __builtin_amdgcn_mfma_f32_16x16x32_bf16(a0, zf[pt][0], acc, 0, 0, 0);
            acc = __builtin_amdgcn_mfma_f32_16x16x32_bf16(a1, zf[pt][1], acc, 0, 0, 0);
            #pragma unroll
            for (int r = 0; r < 4; ++r) {
                const int s = (__builtin_bit_cast(int, acc[r]) & ~1023) | (korg + r);
                best[pt] = min(best[pt], s);
            }
        }
        // rotate buffers
        short* t = bA; bA = bB; bB = bC; bC = t;
    }

    // cross-lane combine over k-groups (bits 4,5 of lane)
    #pragma unroll
    for (int pt = 0; pt < 4; ++pt) {
        #pragma unroll
        for (int m = 16; m <= 32; m <<= 1)
            best[pt] = min(best[pt], __shfl_xor(best[pt], m));
        if (kgrp == 0) smin[qd][pt * 16 + prow] = best[pt];
    }
    __syncthreads();

    // cross-wave combine (4 quadrant-waves)
    if (tid < 64) {
        int bb = min(min(smin[0][tid], smin[1][tid]),
                     min(smin[2][tid], smin[3][tid]));
        cidx[tid] = bb & 1023;
    }
    __syncthreads();

    // ---- output phase: q_st = z + (q - z), partial loss ----
    float* op = out + (size_t)b * C_ * HW_ + hw0;
    const int p  = tid & 63;
    const int c0 = tid >> 6;                  // 0..3
    const float* qrow = emb + (size_t)cidx[p] * C_;
    float sq = 0.f;
    #pragma unroll
    for (int i = 0; i < 16; ++i) {
        const int c = c0 * 16 + i;
        const float zv   = zp[(size_t)c * HW_ + p];
        const float q    = qrow[c];
        const float diff = q - zv;            // matches reference op order
        op[(size_t)c * HW_ + p] = zv + diff;  // q_st = z + (q - z)
        sq = fmaf(diff, diff, sq);
    }
    #pragma unroll
    for (int off = 32; off; off >>= 1) sq += __shfl_xor(sq, off);
    if (lane == 0) red[tid >> 6] = sq;
    __syncthreads();
    if (tid == 0) {
        psum[blk] = (red[0] + red[1]) + (red[2] + red[3]);
        __threadfence();                      // psum visible device-wide
        isLast = (atomicAdd(cnt, 1) == NBLK - 1);
    }
    __syncthreads();

    // ---- last block reduces psum -> loss (fixed order => deterministic) --
    if (isLast) {
        __threadfence();
        float s = (psum[tid] + psum[tid + 256]) + (psum[tid + 512] + psum[tid + 768]);
        #pragma unroll
        for (int off = 32; off; off >>= 1) s += __shfl_xor(s, off);
        if (lane == 0) red[tid >> 6] = s;
        __syncthreads();
        if (tid == 0)
            out[NELEM] = 1.25f * ((red[0] + red[1]) + (red[2] + red[3])) / (float)NELEM;
    }
}

extern "C" void kernel_launch(void* const* d_in, const int* in_sizes, int n_in,
                              void* d_out, int out_size, void* d_ws, size_t ws_size,
                              hipStream_t stream) {
    const float* z   = (const float*)d_in[0];   // [16,64,64,64]
    const float* emb = (const float*)d_in[1];   // [1024,64]
    float* out = (float*)d_out;                 // [4194304 q_st] ++ [1 loss]

    float* psum  = (float*)d_ws;                // 1024 floats
    float* e2    = psum + NBLK;                 // 1024 floats (e2' = 1+|e|^2)
    int*   cnt   = (int*)(e2 + K_);             // 1 int (+pad to 16B)
    short* emb_q = (short*)(cnt + 4);           // 65536 bf16, chunked fragments

    vq_prep<<<(K_ * C_) / (256 * 8), 256, 0, stream>>>(emb, e2, emb_q, cnt);
    vq_main<<<NBLK, 256, 0, stream>>>(z, emb, emb_q, e2, out, psum, cnt);
}